// Round 9
// baseline (287.846 us; speedup 1.0000x reference)
//
#include <hip/hip_runtime.h>

// GraphAttentionLayer: B=8, N=2048, E=128, H=4, D=32. fp32/bf16 sniffed.
// R18 = R15 + k_attn Q-REUSE doubled: 4 q-tiles/wave (64 q rows), 4-way
// key split. Evidence: R17 halved Q-reuse -> L2 traffic 512MB->1GB -> +14us
// (matches per-XCD L2-BW arithmetic) => attn is L2-BW-bound on redundant
// K/V re-reads. This runs the lever in reverse: traffic 512->256MB, same
// 4096 waves (16/CU, grid co-resident), MFMA:VMEM per sub 20:4 (was 10:4),
// 4 chunks/wave serial chain (was 8). Block = 8 waves = 2 wl x 4 key-
// quarters over 128 q rows; COFF fixed offset => quarter-partials additive,
// combined via padded LDS (52KB, 2 blocks/CU=104KB<=160), reduce
// parallelized across quarters (quarter q finalizes tile q).
//  k_pre  : y<6: QKV slices (jt*4, 6 waves/SIMD), y>=6: adj[0] -> bitmask.
//  k_attn : flash, S^T=K@Q^T, exp2 softmax w/ COFF in MFMA C-init, l via
//           ones-MFMA, P.V fp16, direct-from-L2 K/V, XCD swizzle.
//  k_proj : out-projection Oa(bf16) -> d_out (fp32 or bf16), grid (256,4).
// ws: Qg@0 Kg@4M Vth@8M mb@12M Oa@13M (17.2 MB high-water, proven safe).

#define EDIM 128
// log2(e)/sqrt(32); softmax p = 2^(s' + COFF), COFF = -4*log2(e)
#define SCALE2 0.25503483f
#define COFF  -5.7707801f

typedef unsigned int uint32;
typedef float f32x4 __attribute__((ext_vector_type(4)));
typedef short s16x8 __attribute__((ext_vector_type(8)));
typedef _Float16 f16x2 __attribute__((ext_vector_type(2)));
typedef _Float16 f16x4 __attribute__((ext_vector_type(4)));
typedef _Float16 f16x8 __attribute__((ext_vector_type(8)));
typedef __fp16 g16x2 __attribute__((ext_vector_type(2)));

__device__ inline float bf2f(ushort u) { return __uint_as_float(((uint32)u) << 16); }
__device__ inline ushort f2bf(float f) {            // round-to-nearest-even
  uint32 u = __float_as_uint(f);
  u += 0x7fffu + ((u >> 16) & 1u);
  return (ushort)(u >> 16);
}
// pack two fp32 -> two bf16 halfwords (round-half-up; ties-vs-RNE negligible)
__device__ inline uint32 packbf(float a, float b) {
  uint32 ua = __float_as_uint(a) + 0x8000u;
  uint32 ub = __float_as_uint(b) + 0x8000u;
  return __builtin_amdgcn_perm(ub, ua, 0x07060302u);  // {ua.b2,ua.b3,ub.b2,ub.b3}
}
__device__ inline f16x2 pkrtz(float a, float b) {   // v_cvt_pkrtz_f16_f32
  g16x2 t = __builtin_amdgcn_cvt_pkrtz(a, b);
  return __builtin_bit_cast(f16x2, t);
}
__device__ inline float fexp2(float x) {
#if __has_builtin(__builtin_amdgcn_exp2f)
  return __builtin_amdgcn_exp2f(x);
#else
  return __exp2f(x);
#endif
}

__device__ inline f32x4 mfma32(s16x8 a, s16x8 b, f32x4 c) {
  return __builtin_amdgcn_mfma_f32_16x16x32_bf16(a, b, c, 0, 0, 0);
}
__device__ inline f32x4 mfma32h(f16x8 a, f16x8 b, f32x4 c) {
  return __builtin_amdgcn_mfma_f32_16x16x32_f16(a, b, c, 0, 0, 0);
}

// Per-wave dtype sniff on x's first 512 B (L2-hot). Even halfwords: bf16
// data -> exponent in [100,140] ~100%; fp32 data (mantissa bits) ~16%.
__device__ inline int sniff_fp32(const ushort* __restrict__ xus) {
  int lane = threadIdx.x & 63, cnt = 0;
#pragma unroll
  for (int i = 0; i < 4; i++) {
    ushort v = xus[2 * (lane * 4 + i)];
    int ex = (v >> 7) & 0xFF;
    cnt += (ex >= 100 && ex <= 140) ? 1 : 0;
  }
#pragma unroll
  for (int s = 1; s < 64; s <<= 1) cnt += __shfl_xor(cnt, s);
  return cnt < 128;            // 1 = fp32
}

// Load 8 consecutive elements as bf16 frag from fp32 or bf16 array.
__device__ inline s16x8 load8(const void* p, size_t e, int fp32) {
  if (fp32) {
    const float* f = (const float*)p + e;
    float4 lo = *(const float4*)f;
    float4 hi = *(const float4*)(f + 4);
    union { s16x8 s; uint32 u[4]; } r;
    r.u[0] = packbf(lo.x, lo.y);
    r.u[1] = packbf(lo.z, lo.w);
    r.u[2] = packbf(hi.x, hi.y);
    r.u[3] = packbf(hi.z, hi.w);
    return r.s;
  }
  return *(const s16x8*)((const ushort*)p + e);
}
__device__ inline float loads(const void* p, size_t e, int fp32) {
  return fp32 ? ((const float*)p)[e] : bf2f(((const ushort*)p)[e]);
}

// ---------------- fused pre-pass.
// y < 6 : QKV projection slice, jt = y*4 .. y*4+3 (Q: y<2, K: y in 2..3,
//         V: y in 4..5). 6144 waves -> 6 waves/SIMD.
// y >= 6: mask block (y-6)*256+blockIdx.x over adj[0] -> bitmask mb.
__global__ __launch_bounds__(256) void k_pre(const void* __restrict__ x,
                                             const void* __restrict__ w,
                                             const void* __restrict__ bias,
                                             ushort* __restrict__ Qg,
                                             ushort* __restrict__ Kg,
                                             _Float16* __restrict__ Vth,
                                             const int4* __restrict__ adj4,
                                             uint32* __restrict__ mb) {
  if (blockIdx.y >= 6) {                     // ---- mask branch
    int g = ((blockIdx.y - 6) * 256 + blockIdx.x) * 256 + threadIdx.x;
    int4 v = adj4[g];
    int lane = threadIdx.x & 63;
    uint32 nib = (v.x != 0 ? 1u : 0u) | (v.y != 0 ? 2u : 0u) |
                 (v.z != 0 ? 4u : 0u) | (v.w != 0 ? 8u : 0u);
    uint32 wbit = nib << (4 * (lane & 7));
    wbit |= __shfl_xor(wbit, 1);
    wbit |= __shfl_xor(wbit, 2);
    wbit |= __shfl_xor(wbit, 4);
    if ((lane & 7) == 0) mb[g >> 3] = wbit;
    return;
  }

  // ---- QKV branch
  const int fp32 = sniff_fp32((const ushort*)x);
  const int tid = threadIdx.x;
  const int wave = tid >> 6, lane = tid & 63, L = lane & 15, quad = lane >> 4;
  const int mt = blockIdx.x * 64 + wave * 16;
  const int jt0 = blockIdx.y * 4;

  s16x8 a[4];
#pragma unroll
  for (int ks = 0; ks < 4; ks++)
    a[ks] = load8(x, (size_t)(mt + L) * EDIM + ks * 32 + quad * 8, fp32);

  const int bidx = mt >> 11;                 // batch
  const int npos0 = (mt & 2047) + quad * 4;  // n of reg 0 (mult of 4)

  for (int jj = 0; jj < 4; jj++) {
    int jt = jt0 + jj;
    f32x4 acc = {0.f, 0.f, 0.f, 0.f};
#pragma unroll
    for (int ks = 0; ks < 4; ks++) {
      s16x8 bf = load8(w, (size_t)(jt * 16 + L) * EDIM + ks * 32 + quad * 8, fp32);
      acc = mfma32(a[ks], bf, acc);
    }
    int j = jt * 16 + L;
    float badd = loads(bias, j, fp32);
    int jm = j & 127;
    int h = jm >> 5, d = jm & 31;
    int bh = bidx * 4 + h;
    int ch = npos0 >> 7, kk = npos0 & 127;
    if (jt < 8) {              // Q, pre-scaled by log2e/sqrt(D)
#pragma unroll
      for (int r = 0; r < 4; r++)
        Qg[(size_t)bh * 65536 + (size_t)(npos0 + r) * 32 + d] = f2bf((acc[r] + badd) * SCALE2);
    } else if (jt < 16) {      // K: permuted slots + XOR-swizzled granules
      int sub = kk >> 5, k32 = kk & 31, t = k32 >> 3, r8 = k32 & 7;  // r8%4==0
      int slot0 = sub * 32 + ((r8 >> 2) << 4) + t * 4;               // %4 == 0
      size_t kb = (size_t)bh * 65536 + (size_t)ch * 4096;
#pragma unroll
      for (int r = 0; r < 4; r++)
        Kg[kb + (size_t)(slot0 + r) * 32 + (((d >> 3) ^ r) << 3) + (d & 7)] =
            f2bf(acc[r] + badd);
    } else {                   // V fp16, transposed + pre-swizzled
      int g = kk >> 3, e0 = kk & 7;          // e0 in {0,4}
      f16x2 h0 = pkrtz(acc[0] + badd, acc[1] + badd);
      f16x2 h1 = pkrtz(acc[2] + badd, acc[3] + badd);
      f16x4 pk; pk[0] = h0[0]; pk[1] = h0[1]; pk[2] = h1[0]; pk[3] = h1[1];
      *(f16x4*)(Vth + (size_t)bh * 65536 + (size_t)ch * 4096 + d * 128 +
                (g ^ (d & 7)) * 8 + e0) = pk;
    }
  }
}

// ---------------- flash attention, Q-reuse-first: 4 q-tiles/wave, 4-way
// key split. Block = 8 waves = 2 wl x 4 key-quarters over 128 q rows
// (wave = 64 q x 512 keys). K/V fragment loads amortize over 4 q-tiles
// (L2 read traffic 256MB total, half of R15). COFF fixed offset =>
// quarter-partials additive: quarters cross-write via padded LDS, quarter
// q reduces+normalizes+stores tile q. Direct-from-L2 K/V (pre-swizzled
// layouts), no staging, no main-loop barriers. XCD swizzle keeps one bh's
// 256KB K/V panel on one XCD's L2.
__global__ __launch_bounds__(512, 4) void k_attn(const ushort* __restrict__ Qg,
                                                 const ushort* __restrict__ Kg,
                                                 const _Float16* __restrict__ Vth,
                                                 const uint32* __restrict__ mb,
                                                 ushort* __restrict__ Oa) {
  __shared__ float cb[13056];                // 2 wl x 4 tiles x 3 x 544

  const int tid = threadIdx.x;
  const int wv = tid >> 6, lane = tid & 63, L = lane & 15, quad = lane >> 4;
  const int wl = wv & 1, qt = wv >> 1;       // qt = key-quarter (0..3)
  const int bid = blockIdx.x;
  const int bh = ((bid >> 3) & 3) * 8 + (bid & 7);   // inverse of swizzle
  const int qc = bid >> 5;
  const int q0 = qc * 128 + wl * 64;

  const ushort* Qb = Qg + (size_t)bh * 65536;
  s16x8 qf[4];
#pragma unroll
  for (int t = 0; t < 4; t++)
    qf[t] = *(const s16x8*)(Qb + (size_t)(q0 + t * 16 + L) * 32 + quad * 8);

  f32x4 OA0[4], OA1[4], LA[4];
#pragma unroll
  for (int t = 0; t < 4; t++) {
    OA0[t] = (f32x4){0, 0, 0, 0};
    OA1[t] = (f32x4){0, 0, 0, 0};
    LA[t]  = (f32x4){0, 0, 0, 0};
  }
  f16x8 ones;
#pragma unroll
  for (int i = 0; i < 8; i++) ones[i] = (_Float16)1.0f;

  // quarter qt covers chunks qt*4 .. qt*4+3 (byte offset qt*32768)
  const char* Kg8 = (const char*)(Kg + (size_t)bh * 65536) + (size_t)qt * 32768;
  const char* Vg8 = (const char*)(Vth + (size_t)bh * 65536) + (size_t)qt * 32768;
  const int g0 = quad ^ (L & 3);             // swizzled K granule for this lane

  const char* kA = Kg8 + L * 64 + g0 * 16;   // + cc*8192 + sub*2048 (+1024)
  const char* vA = Vg8 + L * 256;            // + cc*8192 (+4096) + vg*16

#define MW4(M, S) ((S) == 0 ? (M).x : (S) == 1 ? (M).y : (S) == 2 ? (M).z : (M).w)

#pragma unroll
  for (int cc = 0; cc < 4; cc++) {
    uint4 mA[4];
#pragma unroll
    for (int t = 0; t < 4; t++)
      mA[t] = *(const uint4*)(mb + (size_t)(q0 + t * 16 + L) * 64 + qt * 16 + cc * 4);
    const char* kc = kA + cc * 8192;
    const char* vc = vA + cc * 8192;

#pragma unroll
    for (int sub = 0; sub < 4; sub++) {
      s16x8 kf0 = *(const s16x8*)(kc + sub * 2048);
      s16x8 kf1 = *(const s16x8*)(kc + sub * 2048 + 1024);
      int vg = (sub * 4 + quad) ^ (L & 7);         // swizzled V granule
      f16x8 vf0 = *(const f16x8*)(vc + vg * 16);
      f16x8 vf1 = *(const f16x8*)(vc + 4096 + vg * 16);

#pragma unroll
      for (int t = 0; t < 4; t++) {
        const f32x4 Zc = {COFF, COFF, COFF, COFF}; // softmax offset via C-init
        f32x4 sA0 = mfma32(kf0, qf[t], Zc), sA1 = mfma32(kf1, qf[t], Zc);

        uint32 mwq = MW4(mA[t], sub) >> (quad * 8);  // keys quad*8 .. +7
        union { f16x8 v; f16x2 h[4]; } pA;
        float a0 = ((mwq >> 0) & 1u) ? fexp2(sA0[0]) : 0.f;
        float a1 = ((mwq >> 1) & 1u) ? fexp2(sA0[1]) : 0.f;
        float a2 = ((mwq >> 2) & 1u) ? fexp2(sA0[2]) : 0.f;
        float a3 = ((mwq >> 3) & 1u) ? fexp2(sA0[3]) : 0.f;
        float a4 = ((mwq >> 4) & 1u) ? fexp2(sA1[0]) : 0.f;
        float a5 = ((mwq >> 5) & 1u) ? fexp2(sA1[1]) : 0.f;
        float a6 = ((mwq >> 6) & 1u) ? fexp2(sA1[2]) : 0.f;
        float a7 = ((mwq >> 7) & 1u) ? fexp2(sA1[3]) : 0.f;
        pA.h[0] = pkrtz(a0, a1); pA.h[1] = pkrtz(a2, a3);
        pA.h[2] = pkrtz(a4, a5); pA.h[3] = pkrtz(a6, a7);

        OA0[t] = mfma32h(vf0, pA.v, OA0[t]);
        OA1[t] = mfma32h(vf1, pA.v, OA1[t]);
        LA[t]  = mfma32h(ones, pA.v, LA[t]);
      }
    }
  }
#undef MW4

  // ---- combine quarters: each wave writes its 3 foreign tiles to LDS
  // (stride-33 pad); quarter q reduces + normalizes + stores tile q.
  __syncthreads();                           // (re)use cb safely
#pragma unroll
  for (int t = 0; t < 4; t++) {
    if (t == qt) continue;                   // wave-uniform guard, static t
    int widx = qt - (qt > t ? 1 : 0);        // 0..2 among writers of tile t
    int base = ((wl * 4 + t) * 3 + widx) * 544;
#pragma unroll
    for (int r = 0; r < 4; r++) {
      cb[base + L * 33 + quad * 4 + r]      = OA0[t][r];
      cb[base + L * 33 + 16 + quad * 4 + r] = OA1[t][r];
    }
    if (quad == 0) cb[base + 528 + L] = LA[t][0];
  }
  __syncthreads();
#pragma unroll
  for (int t = 0; t < 4; t++) {
    if (t != qt) continue;                   // wave-uniform guard, static t
    float lsum = LA[t][0];
#pragma unroll
    for (int s = 0; s < 3; s++) {
      int base = ((wl * 4 + t) * 3 + s) * 544;
#pragma unroll
      for (int r = 0; r < 4; r++) {
        OA0[t][r] += cb[base + L * 33 + quad * 4 + r];
        OA1[t][r] += cb[base + L * 33 + 16 + quad * 4 + r];
      }
      lsum += cb[base + 528 + L];
    }
    float rn = 1.0f / lsum;
    int b = bh >> 2, h = bh & 3;
    size_t ob = ((size_t)(b * 2048 + q0 + t * 16 + L)) * 128 + h * 32 + quad * 4;
    ushort4 p0, p1;
    p0.x = f2bf(OA0[t][0] * rn); p0.y = f2bf(OA0[t][1] * rn);
    p0.z = f2bf(OA0[t][2] * rn); p0.w = f2bf(OA0[t][3] * rn);
    p1.x = f2bf(OA1[t][0] * rn); p1.y = f2bf(OA1[t][1] * rn);
    p1.z = f2bf(OA1[t][2] * rn); p1.w = f2bf(OA1[t][3] * rn);
    *(ushort4*)(Oa + ob) = p0; *(ushort4*)(Oa + ob + 16) = p1;
  }
}

// ---------------- output projection: Oa(bf16) @ out_w^T + out_b -> d_out.
// grid (256,4): blockIdx.y quarters the jt range (src=Oa, dst=d_out, no
// race). 4096 waves -> 4 waves/SIMD.
__global__ __launch_bounds__(256) void k_proj(void* outp, const ushort* Oa,
                                              const void* w, const void* bias,
                                              const ushort* __restrict__ xus) {
  const int fp32 = sniff_fp32(xus);
  const ushort* src = Oa;
  const int tid = threadIdx.x;
  const int wave = tid >> 6, lane = tid & 63, L = lane & 15, quad = lane >> 4;
  const int mt = blockIdx.x * 64 + wave * 16;
  const int jt0 = blockIdx.y * 2;

  s16x8 a[4];
#pragma unroll
  for (int ks = 0; ks < 4; ks++)
    a[ks] = *(const s16x8*)(src + (size_t)(mt + L) * EDIM + ks * 32 + quad * 8);

  for (int jt = jt0; jt < jt0 + 2; jt++) {
    f32x4 acc = {0.f, 0.f, 0.f, 0.f};
#pragma unroll
    for (int ks = 0; ks < 4; ks++) {
      s16x8 bf = load8(w, (size_t)(jt * 16 + L) * EDIM + ks * 32 + quad * 8, fp32);
      acc = mfma32(a[ks], bf, acc);
    }
    float badd = loads(bias, jt * 16 + L, fp32);
#pragma unroll
    for (int r = 0; r < 4; r++) {
      size_t idx = (size_t)(mt + quad * 4 + r) * EDIM + jt * 16 + L;
      if (fp32) ((float*)outp)[idx] = acc[r] + badd;
      else      ((ushort*)outp)[idx] = f2bf(acc[r] + badd);
    }
  }
}

extern "C" void kernel_launch(void* const* d_in, const int* in_sizes, int n_in,
                              void* d_out, int out_size, void* d_ws, size_t ws_size,
                              hipStream_t stream) {
  const void* x   = d_in[0];
  const int*  adj = (const int*)d_in[1];
  const void* ipw = d_in[2];
  const void* ipb = d_in[3];
  const void* ow  = d_in[4];
  const void* ob  = d_in[5];

  char* ws = (char*)d_ws;
  ushort*   Qg  = (ushort*)(ws);
  ushort*   Kg  = (ushort*)(ws + ((size_t)4 << 20));
  _Float16* Vth = (_Float16*)(ws + ((size_t)8 << 20));
  uint32*   mb  = (uint32*)(ws + ((size_t)12 << 20));
  ushort*   Oa  = (ushort*)(ws + ((size_t)13 << 20));

  hipLaunchKernelGGL(k_pre, dim3(256, 22), dim3(256), 0, stream, x, ipw, ipb,
                     Qg, Kg, Vth, (const int4*)adj, mb);
  hipLaunchKernelGGL(k_attn, dim3(512), dim3(512), 0, stream, Qg, Kg, Vth, mb,
                     Oa);
  hipLaunchKernelGGL(k_proj, dim3(256, 4), dim3(256), 0, stream, d_out, Oa, ow, ob,
                     (const ushort*)x);
}

// Round 10
// 285.147 us; speedup vs baseline: 1.0095x; 1.0095x over previous
//
#include <hip/hip_runtime.h>

// GraphAttentionLayer: B=8, N=2048, E=128, H=4, D=32. fp32/bf16 sniffed.
// R19 = R18 + amdgpu_waves_per_eu(4,4) on k_attn. R18's counters exposed a
// REGISTER SPILL: VGPR_Count=64 (allocator aimed for 8 waves/EU; live state
// ~110 regs) -> accumulators spilled to scratch -> WRITE_SIZE 169MB (real
// writes: 8.4MB), FETCH 97MB, 87us. launch_bounds' 2nd arg is only a MIN;
// waves_per_eu(4,4) pins exactly 4 waves/EU -> 128-VGPR budget, no spill.
// Structure unchanged from R18: 4 q-tiles/wave (64 q rows), 4-way key
// split, L2 read traffic 256MB (half of R15), 4-chunk serial chain.
//  k_pre  : y<6: QKV slices (jt*4, 6 waves/SIMD), y>=6: adj[0] -> bitmask.
//  k_attn : flash, S^T=K@Q^T, exp2 softmax w/ COFF in MFMA C-init, l via
//           ones-MFMA, P.V fp16, direct-from-L2 K/V, XCD swizzle, quarter-
//           partials combined via padded LDS (additive: fixed COFF).
//  k_proj : out-projection Oa(bf16) -> d_out (fp32 or bf16), grid (256,4).
// ws: Qg@0 Kg@4M Vth@8M mb@12M Oa@13M (17.2 MB high-water, proven safe).

#define EDIM 128
// log2(e)/sqrt(32); softmax p = 2^(s' + COFF), COFF = -4*log2(e)
#define SCALE2 0.25503483f
#define COFF  -5.7707801f

typedef unsigned int uint32;
typedef float f32x4 __attribute__((ext_vector_type(4)));
typedef short s16x8 __attribute__((ext_vector_type(8)));
typedef _Float16 f16x2 __attribute__((ext_vector_type(2)));
typedef _Float16 f16x4 __attribute__((ext_vector_type(4)));
typedef _Float16 f16x8 __attribute__((ext_vector_type(8)));
typedef __fp16 g16x2 __attribute__((ext_vector_type(2)));

__device__ inline float bf2f(ushort u) { return __uint_as_float(((uint32)u) << 16); }
__device__ inline ushort f2bf(float f) {            // round-to-nearest-even
  uint32 u = __float_as_uint(f);
  u += 0x7fffu + ((u >> 16) & 1u);
  return (ushort)(u >> 16);
}
// pack two fp32 -> two bf16 halfwords (round-half-up; ties-vs-RNE negligible)
__device__ inline uint32 packbf(float a, float b) {
  uint32 ua = __float_as_uint(a) + 0x8000u;
  uint32 ub = __float_as_uint(b) + 0x8000u;
  return __builtin_amdgcn_perm(ub, ua, 0x07060302u);  // {ua.b2,ua.b3,ub.b2,ub.b3}
}
__device__ inline f16x2 pkrtz(float a, float b) {   // v_cvt_pkrtz_f16_f32
  g16x2 t = __builtin_amdgcn_cvt_pkrtz(a, b);
  return __builtin_bit_cast(f16x2, t);
}
__device__ inline float fexp2(float x) {
#if __has_builtin(__builtin_amdgcn_exp2f)
  return __builtin_amdgcn_exp2f(x);
#else
  return __exp2f(x);
#endif
}

__device__ inline f32x4 mfma32(s16x8 a, s16x8 b, f32x4 c) {
  return __builtin_amdgcn_mfma_f32_16x16x32_bf16(a, b, c, 0, 0, 0);
}
__device__ inline f32x4 mfma32h(f16x8 a, f16x8 b, f32x4 c) {
  return __builtin_amdgcn_mfma_f32_16x16x32_f16(a, b, c, 0, 0, 0);
}

// Per-wave dtype sniff on x's first 512 B (L2-hot). Even halfwords: bf16
// data -> exponent in [100,140] ~100%; fp32 data (mantissa bits) ~16%.
__device__ inline int sniff_fp32(const ushort* __restrict__ xus) {
  int lane = threadIdx.x & 63, cnt = 0;
#pragma unroll
  for (int i = 0; i < 4; i++) {
    ushort v = xus[2 * (lane * 4 + i)];
    int ex = (v >> 7) & 0xFF;
    cnt += (ex >= 100 && ex <= 140) ? 1 : 0;
  }
#pragma unroll
  for (int s = 1; s < 64; s <<= 1) cnt += __shfl_xor(cnt, s);
  return cnt < 128;            // 1 = fp32
}

// Load 8 consecutive elements as bf16 frag from fp32 or bf16 array.
__device__ inline s16x8 load8(const void* p, size_t e, int fp32) {
  if (fp32) {
    const float* f = (const float*)p + e;
    float4 lo = *(const float4*)f;
    float4 hi = *(const float4*)(f + 4);
    union { s16x8 s; uint32 u[4]; } r;
    r.u[0] = packbf(lo.x, lo.y);
    r.u[1] = packbf(lo.z, lo.w);
    r.u[2] = packbf(hi.x, hi.y);
    r.u[3] = packbf(hi.z, hi.w);
    return r.s;
  }
  return *(const s16x8*)((const ushort*)p + e);
}
__device__ inline float loads(const void* p, size_t e, int fp32) {
  return fp32 ? ((const float*)p)[e] : bf2f(((const ushort*)p)[e]);
}

// ---------------- fused pre-pass.
// y < 6 : QKV projection slice, jt = y*4 .. y*4+3 (Q: y<2, K: y in 2..3,
//         V: y in 4..5). 6144 waves -> 6 waves/SIMD.
// y >= 6: mask block (y-6)*256+blockIdx.x over adj[0] -> bitmask mb.
__global__ __launch_bounds__(256) void k_pre(const void* __restrict__ x,
                                             const void* __restrict__ w,
                                             const void* __restrict__ bias,
                                             ushort* __restrict__ Qg,
                                             ushort* __restrict__ Kg,
                                             _Float16* __restrict__ Vth,
                                             const int4* __restrict__ adj4,
                                             uint32* __restrict__ mb) {
  if (blockIdx.y >= 6) {                     // ---- mask branch
    int g = ((blockIdx.y - 6) * 256 + blockIdx.x) * 256 + threadIdx.x;
    int4 v = adj4[g];
    int lane = threadIdx.x & 63;
    uint32 nib = (v.x != 0 ? 1u : 0u) | (v.y != 0 ? 2u : 0u) |
                 (v.z != 0 ? 4u : 0u) | (v.w != 0 ? 8u : 0u);
    uint32 wbit = nib << (4 * (lane & 7));
    wbit |= __shfl_xor(wbit, 1);
    wbit |= __shfl_xor(wbit, 2);
    wbit |= __shfl_xor(wbit, 4);
    if ((lane & 7) == 0) mb[g >> 3] = wbit;
    return;
  }

  // ---- QKV branch
  const int fp32 = sniff_fp32((const ushort*)x);
  const int tid = threadIdx.x;
  const int wave = tid >> 6, lane = tid & 63, L = lane & 15, quad = lane >> 4;
  const int mt = blockIdx.x * 64 + wave * 16;
  const int jt0 = blockIdx.y * 4;

  s16x8 a[4];
#pragma unroll
  for (int ks = 0; ks < 4; ks++)
    a[ks] = load8(x, (size_t)(mt + L) * EDIM + ks * 32 + quad * 8, fp32);

  const int bidx = mt >> 11;                 // batch
  const int npos0 = (mt & 2047) + quad * 4;  // n of reg 0 (mult of 4)

  for (int jj = 0; jj < 4; jj++) {
    int jt = jt0 + jj;
    f32x4 acc = {0.f, 0.f, 0.f, 0.f};
#pragma unroll
    for (int ks = 0; ks < 4; ks++) {
      s16x8 bf = load8(w, (size_t)(jt * 16 + L) * EDIM + ks * 32 + quad * 8, fp32);
      acc = mfma32(a[ks], bf, acc);
    }
    int j = jt * 16 + L;
    float badd = loads(bias, j, fp32);
    int jm = j & 127;
    int h = jm >> 5, d = jm & 31;
    int bh = bidx * 4 + h;
    int ch = npos0 >> 7, kk = npos0 & 127;
    if (jt < 8) {              // Q, pre-scaled by log2e/sqrt(D)
#pragma unroll
      for (int r = 0; r < 4; r++)
        Qg[(size_t)bh * 65536 + (size_t)(npos0 + r) * 32 + d] = f2bf((acc[r] + badd) * SCALE2);
    } else if (jt < 16) {      // K: permuted slots + XOR-swizzled granules
      int sub = kk >> 5, k32 = kk & 31, t = k32 >> 3, r8 = k32 & 7;  // r8%4==0
      int slot0 = sub * 32 + ((r8 >> 2) << 4) + t * 4;               // %4 == 0
      size_t kb = (size_t)bh * 65536 + (size_t)ch * 4096;
#pragma unroll
      for (int r = 0; r < 4; r++)
        Kg[kb + (size_t)(slot0 + r) * 32 + (((d >> 3) ^ r) << 3) + (d & 7)] =
            f2bf(acc[r] + badd);
    } else {                   // V fp16, transposed + pre-swizzled
      int g = kk >> 3, e0 = kk & 7;          // e0 in {0,4}
      f16x2 h0 = pkrtz(acc[0] + badd, acc[1] + badd);
      f16x2 h1 = pkrtz(acc[2] + badd, acc[3] + badd);
      f16x4 pk; pk[0] = h0[0]; pk[1] = h0[1]; pk[2] = h1[0]; pk[3] = h1[1];
      *(f16x4*)(Vth + (size_t)bh * 65536 + (size_t)ch * 4096 + d * 128 +
                (g ^ (d & 7)) * 8 + e0) = pk;
    }
  }
}

// ---------------- flash attention, Q-reuse-first: 4 q-tiles/wave, 4-way
// key split. Block = 8 waves = 2 wl x 4 key-quarters over 128 q rows
// (wave = 64 q x 512 keys). K/V fragment loads amortize over 4 q-tiles
// (L2 read traffic 256MB total, half of R15). COFF fixed offset =>
// quarter-partials additive: quarters cross-write via padded LDS, quarter
// q reduces+normalizes+stores tile q. Direct-from-L2 K/V (pre-swizzled
// layouts), no staging, no main-loop barriers. XCD swizzle keeps one bh's
// 256KB K/V panel on one XCD's L2. waves_per_eu(4,4) pins the register
// budget at 128 VGPR (R18's spill: allocator chose 64 and scratch-spilled
// the accumulators -> 169MB phantom WRITE_SIZE).
__global__ __launch_bounds__(512)
__attribute__((amdgpu_waves_per_eu(4, 4)))
void k_attn(const ushort* __restrict__ Qg,
            const ushort* __restrict__ Kg,
            const _Float16* __restrict__ Vth,
            const uint32* __restrict__ mb,
            ushort* __restrict__ Oa) {
  __shared__ float cb[13056];                // 2 wl x 4 tiles x 3 x 544

  const int tid = threadIdx.x;
  const int wv = tid >> 6, lane = tid & 63, L = lane & 15, quad = lane >> 4;
  const int wl = wv & 1, qt = wv >> 1;       // qt = key-quarter (0..3)
  const int bid = blockIdx.x;
  const int bh = ((bid >> 3) & 3) * 8 + (bid & 7);   // inverse of swizzle
  const int qc = bid >> 5;
  const int q0 = qc * 128 + wl * 64;

  const ushort* Qb = Qg + (size_t)bh * 65536;
  s16x8 qf[4];
#pragma unroll
  for (int t = 0; t < 4; t++)
    qf[t] = *(const s16x8*)(Qb + (size_t)(q0 + t * 16 + L) * 32 + quad * 8);

  f32x4 OA0[4], OA1[4], LA[4];
#pragma unroll
  for (int t = 0; t < 4; t++) {
    OA0[t] = (f32x4){0, 0, 0, 0};
    OA1[t] = (f32x4){0, 0, 0, 0};
    LA[t]  = (f32x4){0, 0, 0, 0};
  }
  f16x8 ones;
#pragma unroll
  for (int i = 0; i < 8; i++) ones[i] = (_Float16)1.0f;

  // quarter qt covers chunks qt*4 .. qt*4+3 (byte offset qt*32768)
  const char* Kg8 = (const char*)(Kg + (size_t)bh * 65536) + (size_t)qt * 32768;
  const char* Vg8 = (const char*)(Vth + (size_t)bh * 65536) + (size_t)qt * 32768;
  const int g0 = quad ^ (L & 3);             // swizzled K granule for this lane

  const char* kA = Kg8 + L * 64 + g0 * 16;   // + cc*8192 + sub*2048 (+1024)
  const char* vA = Vg8 + L * 256;            // + cc*8192 (+4096) + vg*16

#define MW4(M, S) ((S) == 0 ? (M).x : (S) == 1 ? (M).y : (S) == 2 ? (M).z : (M).w)

#pragma unroll
  for (int cc = 0; cc < 4; cc++) {
    uint4 mA[4];
#pragma unroll
    for (int t = 0; t < 4; t++)
      mA[t] = *(const uint4*)(mb + (size_t)(q0 + t * 16 + L) * 64 + qt * 16 + cc * 4);
    const char* kc = kA + cc * 8192;
    const char* vc = vA + cc * 8192;

#pragma unroll
    for (int sub = 0; sub < 4; sub++) {
      s16x8 kf0 = *(const s16x8*)(kc + sub * 2048);
      s16x8 kf1 = *(const s16x8*)(kc + sub * 2048 + 1024);
      int vg = (sub * 4 + quad) ^ (L & 7);         // swizzled V granule
      f16x8 vf0 = *(const f16x8*)(vc + vg * 16);
      f16x8 vf1 = *(const f16x8*)(vc + 4096 + vg * 16);

#pragma unroll
      for (int t = 0; t < 4; t++) {
        const f32x4 Zc = {COFF, COFF, COFF, COFF}; // softmax offset via C-init
        f32x4 sA0 = mfma32(kf0, qf[t], Zc), sA1 = mfma32(kf1, qf[t], Zc);

        uint32 mwq = MW4(mA[t], sub) >> (quad * 8);  // keys quad*8 .. +7
        union { f16x8 v; f16x2 h[4]; } pA;
        float a0 = ((mwq >> 0) & 1u) ? fexp2(sA0[0]) : 0.f;
        float a1 = ((mwq >> 1) & 1u) ? fexp2(sA0[1]) : 0.f;
        float a2 = ((mwq >> 2) & 1u) ? fexp2(sA0[2]) : 0.f;
        float a3 = ((mwq >> 3) & 1u) ? fexp2(sA0[3]) : 0.f;
        float a4 = ((mwq >> 4) & 1u) ? fexp2(sA1[0]) : 0.f;
        float a5 = ((mwq >> 5) & 1u) ? fexp2(sA1[1]) : 0.f;
        float a6 = ((mwq >> 6) & 1u) ? fexp2(sA1[2]) : 0.f;
        float a7 = ((mwq >> 7) & 1u) ? fexp2(sA1[3]) : 0.f;
        pA.h[0] = pkrtz(a0, a1); pA.h[1] = pkrtz(a2, a3);
        pA.h[2] = pkrtz(a4, a5); pA.h[3] = pkrtz(a6, a7);

        OA0[t] = mfma32h(vf0, pA.v, OA0[t]);
        OA1[t] = mfma32h(vf1, pA.v, OA1[t]);
        LA[t]  = mfma32h(ones, pA.v, LA[t]);
      }
    }
  }
#undef MW4

  // ---- combine quarters: each wave writes its 3 foreign tiles to LDS
  // (stride-33 pad); quarter q reduces + normalizes + stores tile q.
  __syncthreads();                           // (re)use cb safely
#pragma unroll
  for (int t = 0; t < 4; t++) {
    if (t == qt) continue;                   // wave-uniform guard, static t
    int widx = qt - (qt > t ? 1 : 0);        // 0..2 among writers of tile t
    int base = ((wl * 4 + t) * 3 + widx) * 544;
#pragma unroll
    for (int r = 0; r < 4; r++) {
      cb[base + L * 33 + quad * 4 + r]      = OA0[t][r];
      cb[base + L * 33 + 16 + quad * 4 + r] = OA1[t][r];
    }
    if (quad == 0) cb[base + 528 + L] = LA[t][0];
  }
  __syncthreads();
#pragma unroll
  for (int t = 0; t < 4; t++) {
    if (t != qt) continue;                   // wave-uniform guard, static t
    float lsum = LA[t][0];
#pragma unroll
    for (int s = 0; s < 3; s++) {
      int base = ((wl * 4 + t) * 3 + s) * 544;
#pragma unroll
      for (int r = 0; r < 4; r++) {
        OA0[t][r] += cb[base + L * 33 + quad * 4 + r];
        OA1[t][r] += cb[base + L * 33 + 16 + quad * 4 + r];
      }
      lsum += cb[base + 528 + L];
    }
    float rn = 1.0f / lsum;
    int b = bh >> 2, h = bh & 3;
    size_t ob = ((size_t)(b * 2048 + q0 + t * 16 + L)) * 128 + h * 32 + quad * 4;
    ushort4 p0, p1;
    p0.x = f2bf(OA0[t][0] * rn); p0.y = f2bf(OA0[t][1] * rn);
    p0.z = f2bf(OA0[t][2] * rn); p0.w = f2bf(OA0[t][3] * rn);
    p1.x = f2bf(OA1[t][0] * rn); p1.y = f2bf(OA1[t][1] * rn);
    p1.z = f2bf(OA1[t][2] * rn); p1.w = f2bf(OA1[t][3] * rn);
    *(ushort4*)(Oa + ob) = p0; *(ushort4*)(Oa + ob + 16) = p1;
  }
}

// ---------------- output projection: Oa(bf16) @ out_w^T + out_b -> d_out.
// grid (256,4): blockIdx.y quarters the jt range (src=Oa, dst=d_out, no
// race). 4096 waves -> 4 waves/SIMD.
__global__ __launch_bounds__(256) void k_proj(void* outp, const ushort* Oa,
                                              const void* w, const void* bias,
                                              const ushort* __restrict__ xus) {
  const int fp32 = sniff_fp32(xus);
  const ushort* src = Oa;
  const int tid = threadIdx.x;
  const int wave = tid >> 6, lane = tid & 63, L = lane & 15, quad = lane >> 4;
  const int mt = blockIdx.x * 64 + wave * 16;
  const int jt0 = blockIdx.y * 2;

  s16x8 a[4];
#pragma unroll
  for (int ks = 0; ks < 4; ks++)
    a[ks] = *(const s16x8*)(src + (size_t)(mt + L) * EDIM + ks * 32 + quad * 8);

  for (int jt = jt0; jt < jt0 + 2; jt++) {
    f32x4 acc = {0.f, 0.f, 0.f, 0.f};
#pragma unroll
    for (int ks = 0; ks < 4; ks++) {
      s16x8 bf = load8(w, (size_t)(jt * 16 + L) * EDIM + ks * 32 + quad * 8, fp32);
      acc = mfma32(a[ks], bf, acc);
    }
    float badd = loads(bias, jt * 16 + L, fp32);
#pragma unroll
    for (int r = 0; r < 4; r++) {
      size_t idx = (size_t)(mt + quad * 4 + r) * EDIM + jt * 16 + L;
      if (fp32) ((float*)outp)[idx] = acc[r] + badd;
      else      ((ushort*)outp)[idx] = f2bf(acc[r] + badd);
    }
  }
}

extern "C" void kernel_launch(void* const* d_in, const int* in_sizes, int n_in,
                              void* d_out, int out_size, void* d_ws, size_t ws_size,
                              hipStream_t stream) {
  const void* x   = d_in[0];
  const int*  adj = (const int*)d_in[1];
  const void* ipw = d_in[2];
  const void* ipb = d_in[3];
  const void* ow  = d_in[4];
  const void* ob  = d_in[5];

  char* ws = (char*)d_ws;
  ushort*   Qg  = (ushort*)(ws);
  ushort*   Kg  = (ushort*)(ws + ((size_t)4 << 20));
  _Float16* Vth = (_Float16*)(ws + ((size_t)8 << 20));
  uint32*   mb  = (uint32*)(ws + ((size_t)12 << 20));
  ushort*   Oa  = (ushort*)(ws + ((size_t)13 << 20));

  hipLaunchKernelGGL(k_pre, dim3(256, 22), dim3(256), 0, stream, x, ipw, ipb,
                     Qg, Kg, Vth, (const int4*)adj, mb);
  hipLaunchKernelGGL(k_attn, dim3(512), dim3(512), 0, stream, Qg, Kg, Vth, mb,
                     Oa);
  hipLaunchKernelGGL(k_proj, dim3(256, 4), dim3(256), 0, stream, d_out, Oa, ow, ob,
                     (const ushort*)x);
}

// Round 11
// 253.009 us; speedup vs baseline: 1.1377x; 1.1270x over previous
//
#include <hip/hip_runtime.h>

// GraphAttentionLayer: B=8, N=2048, E=128, H=4, D=32. fp32/bf16 sniffed.
// R20 = R18 structure + __launch_bounds__(512, 2) on k_attn. Root cause of
// R18/R19's 87/84us attn: the launch_bounds 2nd arg behaves as CUDA-style
// min-BLOCKS-per-CU -> (512,4) = 4blk x 8w = 32 waves/CU = 8 w/SIMD ->
// hard 64-VGPR budget -> the 4-qtile ~110-reg state scratch-spilled
// (WRITE_SIZE 131-169MB vs real 8.4MB). R19's amdgpu_waves_per_eu attr was
// ignored (VGPR stayed 64). (512,2) -> >=128 VGPR budget, no spill;
// occupancy 16 waves/CU (same as R15) but HALF R15's L2 read traffic
// (256MB) and 4x MFMA:VMEM (Q-reuse lever proven by R17's inverse).
//  k_pre  : y<6: QKV slices (jt*4, 6 waves/SIMD), y>=6: adj[0] -> bitmask.
//  k_attn : flash, 4 q-tiles/wave, 4-way key split, S^T=K@Q^T, exp2
//           softmax w/ COFF in MFMA C-init, l via ones-MFMA, P.V fp16,
//           direct-from-L2 K/V, XCD swizzle, LDS combine of quarters.
//  k_proj : out-projection Oa(bf16) -> d_out (fp32 or bf16), grid (256,4).
// ws: Qg@0 Kg@4M Vth@8M mb@12M Oa@13M (17.2 MB high-water, proven safe).

#define EDIM 128
// log2(e)/sqrt(32); softmax p = 2^(s' + COFF), COFF = -4*log2(e)
#define SCALE2 0.25503483f
#define COFF  -5.7707801f

typedef unsigned int uint32;
typedef float f32x4 __attribute__((ext_vector_type(4)));
typedef short s16x8 __attribute__((ext_vector_type(8)));
typedef _Float16 f16x2 __attribute__((ext_vector_type(2)));
typedef _Float16 f16x4 __attribute__((ext_vector_type(4)));
typedef _Float16 f16x8 __attribute__((ext_vector_type(8)));
typedef __fp16 g16x2 __attribute__((ext_vector_type(2)));

__device__ inline float bf2f(ushort u) { return __uint_as_float(((uint32)u) << 16); }
__device__ inline ushort f2bf(float f) {            // round-to-nearest-even
  uint32 u = __float_as_uint(f);
  u += 0x7fffu + ((u >> 16) & 1u);
  return (ushort)(u >> 16);
}
// pack two fp32 -> two bf16 halfwords (round-half-up; ties-vs-RNE negligible)
__device__ inline uint32 packbf(float a, float b) {
  uint32 ua = __float_as_uint(a) + 0x8000u;
  uint32 ub = __float_as_uint(b) + 0x8000u;
  return __builtin_amdgcn_perm(ub, ua, 0x07060302u);  // {ua.b2,ua.b3,ub.b2,ub.b3}
}
__device__ inline f16x2 pkrtz(float a, float b) {   // v_cvt_pkrtz_f16_f32
  g16x2 t = __builtin_amdgcn_cvt_pkrtz(a, b);
  return __builtin_bit_cast(f16x2, t);
}
__device__ inline float fexp2(float x) {
#if __has_builtin(__builtin_amdgcn_exp2f)
  return __builtin_amdgcn_exp2f(x);
#else
  return __exp2f(x);
#endif
}

__device__ inline f32x4 mfma32(s16x8 a, s16x8 b, f32x4 c) {
  return __builtin_amdgcn_mfma_f32_16x16x32_bf16(a, b, c, 0, 0, 0);
}
__device__ inline f32x4 mfma32h(f16x8 a, f16x8 b, f32x4 c) {
  return __builtin_amdgcn_mfma_f32_16x16x32_f16(a, b, c, 0, 0, 0);
}

// Per-wave dtype sniff on x's first 512 B (L2-hot). Even halfwords: bf16
// data -> exponent in [100,140] ~100%; fp32 data (mantissa bits) ~16%.
__device__ inline int sniff_fp32(const ushort* __restrict__ xus) {
  int lane = threadIdx.x & 63, cnt = 0;
#pragma unroll
  for (int i = 0; i < 4; i++) {
    ushort v = xus[2 * (lane * 4 + i)];
    int ex = (v >> 7) & 0xFF;
    cnt += (ex >= 100 && ex <= 140) ? 1 : 0;
  }
#pragma unroll
  for (int s = 1; s < 64; s <<= 1) cnt += __shfl_xor(cnt, s);
  return cnt < 128;            // 1 = fp32
}

// Load 8 consecutive elements as bf16 frag from fp32 or bf16 array.
__device__ inline s16x8 load8(const void* p, size_t e, int fp32) {
  if (fp32) {
    const float* f = (const float*)p + e;
    float4 lo = *(const float4*)f;
    float4 hi = *(const float4*)(f + 4);
    union { s16x8 s; uint32 u[4]; } r;
    r.u[0] = packbf(lo.x, lo.y);
    r.u[1] = packbf(lo.z, lo.w);
    r.u[2] = packbf(hi.x, hi.y);
    r.u[3] = packbf(hi.z, hi.w);
    return r.s;
  }
  return *(const s16x8*)((const ushort*)p + e);
}
__device__ inline float loads(const void* p, size_t e, int fp32) {
  return fp32 ? ((const float*)p)[e] : bf2f(((const ushort*)p)[e]);
}

// ---------------- fused pre-pass.
// y < 6 : QKV projection slice, jt = y*4 .. y*4+3 (Q: y<2, K: y in 2..3,
//         V: y in 4..5). 6144 waves -> 6 waves/SIMD.
// y >= 6: mask block (y-6)*256+blockIdx.x over adj[0] -> bitmask mb.
__global__ __launch_bounds__(256) void k_pre(const void* __restrict__ x,
                                             const void* __restrict__ w,
                                             const void* __restrict__ bias,
                                             ushort* __restrict__ Qg,
                                             ushort* __restrict__ Kg,
                                             _Float16* __restrict__ Vth,
                                             const int4* __restrict__ adj4,
                                             uint32* __restrict__ mb) {
  if (blockIdx.y >= 6) {                     // ---- mask branch
    int g = ((blockIdx.y - 6) * 256 + blockIdx.x) * 256 + threadIdx.x;
    int4 v = adj4[g];
    int lane = threadIdx.x & 63;
    uint32 nib = (v.x != 0 ? 1u : 0u) | (v.y != 0 ? 2u : 0u) |
                 (v.z != 0 ? 4u : 0u) | (v.w != 0 ? 8u : 0u);
    uint32 wbit = nib << (4 * (lane & 7));
    wbit |= __shfl_xor(wbit, 1);
    wbit |= __shfl_xor(wbit, 2);
    wbit |= __shfl_xor(wbit, 4);
    if ((lane & 7) == 0) mb[g >> 3] = wbit;
    return;
  }

  // ---- QKV branch
  const int fp32 = sniff_fp32((const ushort*)x);
  const int tid = threadIdx.x;
  const int wave = tid >> 6, lane = tid & 63, L = lane & 15, quad = lane >> 4;
  const int mt = blockIdx.x * 64 + wave * 16;
  const int jt0 = blockIdx.y * 4;

  s16x8 a[4];
#pragma unroll
  for (int ks = 0; ks < 4; ks++)
    a[ks] = load8(x, (size_t)(mt + L) * EDIM + ks * 32 + quad * 8, fp32);

  const int bidx = mt >> 11;                 // batch
  const int npos0 = (mt & 2047) + quad * 4;  // n of reg 0 (mult of 4)

  for (int jj = 0; jj < 4; jj++) {
    int jt = jt0 + jj;
    f32x4 acc = {0.f, 0.f, 0.f, 0.f};
#pragma unroll
    for (int ks = 0; ks < 4; ks++) {
      s16x8 bf = load8(w, (size_t)(jt * 16 + L) * EDIM + ks * 32 + quad * 8, fp32);
      acc = mfma32(a[ks], bf, acc);
    }
    int j = jt * 16 + L;
    float badd = loads(bias, j, fp32);
    int jm = j & 127;
    int h = jm >> 5, d = jm & 31;
    int bh = bidx * 4 + h;
    int ch = npos0 >> 7, kk = npos0 & 127;
    if (jt < 8) {              // Q, pre-scaled by log2e/sqrt(D)
#pragma unroll
      for (int r = 0; r < 4; r++)
        Qg[(size_t)bh * 65536 + (size_t)(npos0 + r) * 32 + d] = f2bf((acc[r] + badd) * SCALE2);
    } else if (jt < 16) {      // K: permuted slots + XOR-swizzled granules
      int sub = kk >> 5, k32 = kk & 31, t = k32 >> 3, r8 = k32 & 7;  // r8%4==0
      int slot0 = sub * 32 + ((r8 >> 2) << 4) + t * 4;               // %4 == 0
      size_t kb = (size_t)bh * 65536 + (size_t)ch * 4096;
#pragma unroll
      for (int r = 0; r < 4; r++)
        Kg[kb + (size_t)(slot0 + r) * 32 + (((d >> 3) ^ r) << 3) + (d & 7)] =
            f2bf(acc[r] + badd);
    } else {                   // V fp16, transposed + pre-swizzled
      int g = kk >> 3, e0 = kk & 7;          // e0 in {0,4}
      f16x2 h0 = pkrtz(acc[0] + badd, acc[1] + badd);
      f16x2 h1 = pkrtz(acc[2] + badd, acc[3] + badd);
      f16x4 pk; pk[0] = h0[0]; pk[1] = h0[1]; pk[2] = h1[0]; pk[3] = h1[1];
      *(f16x4*)(Vth + (size_t)bh * 65536 + (size_t)ch * 4096 + d * 128 +
                (g ^ (d & 7)) * 8 + e0) = pk;
    }
  }
}

// ---------------- flash attention, Q-reuse-first: 4 q-tiles/wave, 4-way
// key split. Block = 8 waves = 2 wl x 4 key-quarters over 128 q rows
// (wave = 64 q x 512 keys). K/V fragment loads amortize over 4 q-tiles
// (L2 read traffic 256MB total, half of R15). COFF fixed offset =>
// quarter-partials additive: quarters cross-write via padded LDS, quarter
// q reduces+normalizes+stores tile q. Direct-from-L2 K/V (pre-swizzled
// layouts), no staging, no main-loop barriers. XCD swizzle keeps one bh's
// 256KB K/V panel on one XCD's L2. launch_bounds(512,2): min 2 blocks/CU
// -> >=128-VGPR budget; (512,4) hard-capped 64 VGPR and spilled the
// ~110-reg live state (R18/R19: 131-169MB phantom WRITE_SIZE).
__global__ __launch_bounds__(512, 2)
void k_attn(const ushort* __restrict__ Qg,
            const ushort* __restrict__ Kg,
            const _Float16* __restrict__ Vth,
            const uint32* __restrict__ mb,
            ushort* __restrict__ Oa) {
  __shared__ float cb[13056];                // 2 wl x 4 tiles x 3 x 544

  const int tid = threadIdx.x;
  const int wv = tid >> 6, lane = tid & 63, L = lane & 15, quad = lane >> 4;
  const int wl = wv & 1, qt = wv >> 1;       // qt = key-quarter (0..3)
  const int bid = blockIdx.x;
  const int bh = ((bid >> 3) & 3) * 8 + (bid & 7);   // inverse of swizzle
  const int qc = bid >> 5;
  const int q0 = qc * 128 + wl * 64;

  const ushort* Qb = Qg + (size_t)bh * 65536;
  s16x8 qf[4];
#pragma unroll
  for (int t = 0; t < 4; t++)
    qf[t] = *(const s16x8*)(Qb + (size_t)(q0 + t * 16 + L) * 32 + quad * 8);

  f32x4 OA0[4], OA1[4], LA[4];
#pragma unroll
  for (int t = 0; t < 4; t++) {
    OA0[t] = (f32x4){0, 0, 0, 0};
    OA1[t] = (f32x4){0, 0, 0, 0};
    LA[t]  = (f32x4){0, 0, 0, 0};
  }
  f16x8 ones;
#pragma unroll
  for (int i = 0; i < 8; i++) ones[i] = (_Float16)1.0f;

  // quarter qt covers chunks qt*4 .. qt*4+3 (byte offset qt*32768)
  const char* Kg8 = (const char*)(Kg + (size_t)bh * 65536) + (size_t)qt * 32768;
  const char* Vg8 = (const char*)(Vth + (size_t)bh * 65536) + (size_t)qt * 32768;
  const int g0 = quad ^ (L & 3);             // swizzled K granule for this lane

  const char* kA = Kg8 + L * 64 + g0 * 16;   // + cc*8192 + sub*2048 (+1024)
  const char* vA = Vg8 + L * 256;            // + cc*8192 (+4096) + vg*16

#define MW4(M, S) ((S) == 0 ? (M).x : (S) == 1 ? (M).y : (S) == 2 ? (M).z : (M).w)

#pragma unroll
  for (int cc = 0; cc < 4; cc++) {
    uint4 mA[4];
#pragma unroll
    for (int t = 0; t < 4; t++)
      mA[t] = *(const uint4*)(mb + (size_t)(q0 + t * 16 + L) * 64 + qt * 16 + cc * 4);
    const char* kc = kA + cc * 8192;
    const char* vc = vA + cc * 8192;

#pragma unroll
    for (int sub = 0; sub < 4; sub++) {
      s16x8 kf0 = *(const s16x8*)(kc + sub * 2048);
      s16x8 kf1 = *(const s16x8*)(kc + sub * 2048 + 1024);
      int vg = (sub * 4 + quad) ^ (L & 7);         // swizzled V granule
      f16x8 vf0 = *(const f16x8*)(vc + vg * 16);
      f16x8 vf1 = *(const f16x8*)(vc + 4096 + vg * 16);

#pragma unroll
      for (int t = 0; t < 4; t++) {
        const f32x4 Zc = {COFF, COFF, COFF, COFF}; // softmax offset via C-init
        f32x4 sA0 = mfma32(kf0, qf[t], Zc), sA1 = mfma32(kf1, qf[t], Zc);

        uint32 mwq = MW4(mA[t], sub) >> (quad * 8);  // keys quad*8 .. +7
        union { f16x8 v; f16x2 h[4]; } pA;
        float a0 = ((mwq >> 0) & 1u) ? fexp2(sA0[0]) : 0.f;
        float a1 = ((mwq >> 1) & 1u) ? fexp2(sA0[1]) : 0.f;
        float a2 = ((mwq >> 2) & 1u) ? fexp2(sA0[2]) : 0.f;
        float a3 = ((mwq >> 3) & 1u) ? fexp2(sA0[3]) : 0.f;
        float a4 = ((mwq >> 4) & 1u) ? fexp2(sA1[0]) : 0.f;
        float a5 = ((mwq >> 5) & 1u) ? fexp2(sA1[1]) : 0.f;
        float a6 = ((mwq >> 6) & 1u) ? fexp2(sA1[2]) : 0.f;
        float a7 = ((mwq >> 7) & 1u) ? fexp2(sA1[3]) : 0.f;
        pA.h[0] = pkrtz(a0, a1); pA.h[1] = pkrtz(a2, a3);
        pA.h[2] = pkrtz(a4, a5); pA.h[3] = pkrtz(a6, a7);

        OA0[t] = mfma32h(vf0, pA.v, OA0[t]);
        OA1[t] = mfma32h(vf1, pA.v, OA1[t]);
        LA[t]  = mfma32h(ones, pA.v, LA[t]);
      }
    }
  }
#undef MW4

  // ---- combine quarters: each wave writes its 3 foreign tiles to LDS
  // (stride-33 pad); quarter q reduces + normalizes + stores tile q.
  __syncthreads();                           // (re)use cb safely
#pragma unroll
  for (int t = 0; t < 4; t++) {
    if (t == qt) continue;                   // wave-uniform guard, static t
    int widx = qt - (qt > t ? 1 : 0);        // 0..2 among writers of tile t
    int base = ((wl * 4 + t) * 3 + widx) * 544;
#pragma unroll
    for (int r = 0; r < 4; r++) {
      cb[base + L * 33 + quad * 4 + r]      = OA0[t][r];
      cb[base + L * 33 + 16 + quad * 4 + r] = OA1[t][r];
    }
    if (quad == 0) cb[base + 528 + L] = LA[t][0];
  }
  __syncthreads();
#pragma unroll
  for (int t = 0; t < 4; t++) {
    if (t != qt) continue;                   // wave-uniform guard, static t
    float lsum = LA[t][0];
#pragma unroll
    for (int s = 0; s < 3; s++) {
      int base = ((wl * 4 + t) * 3 + s) * 544;
#pragma unroll
      for (int r = 0; r < 4; r++) {
        OA0[t][r] += cb[base + L * 33 + quad * 4 + r];
        OA1[t][r] += cb[base + L * 33 + 16 + quad * 4 + r];
      }
      lsum += cb[base + 528 + L];
    }
    float rn = 1.0f / lsum;
    int b = bh >> 2, h = bh & 3;
    size_t ob = ((size_t)(b * 2048 + q0 + t * 16 + L)) * 128 + h * 32 + quad * 4;
    ushort4 p0, p1;
    p0.x = f2bf(OA0[t][0] * rn); p0.y = f2bf(OA0[t][1] * rn);
    p0.z = f2bf(OA0[t][2] * rn); p0.w = f2bf(OA0[t][3] * rn);
    p1.x = f2bf(OA1[t][0] * rn); p1.y = f2bf(OA1[t][1] * rn);
    p1.z = f2bf(OA1[t][2] * rn); p1.w = f2bf(OA1[t][3] * rn);
    *(ushort4*)(Oa + ob) = p0; *(ushort4*)(Oa + ob + 16) = p1;
  }
}

// ---------------- output projection: Oa(bf16) @ out_w^T + out_b -> d_out.
// grid (256,4): blockIdx.y quarters the jt range (src=Oa, dst=d_out, no
// race). 4096 waves -> 4 waves/SIMD.
__global__ __launch_bounds__(256) void k_proj(void* outp, const ushort* Oa,
                                              const void* w, const void* bias,
                                              const ushort* __restrict__ xus) {
  const int fp32 = sniff_fp32(xus);
  const ushort* src = Oa;
  const int tid = threadIdx.x;
  const int wave = tid >> 6, lane = tid & 63, L = lane & 15, quad = lane >> 4;
  const int mt = blockIdx.x * 64 + wave * 16;
  const int jt0 = blockIdx.y * 2;

  s16x8 a[4];
#pragma unroll
  for (int ks = 0; ks < 4; ks++)
    a[ks] = *(const s16x8*)(src + (size_t)(mt + L) * EDIM + ks * 32 + quad * 8);

  for (int jt = jt0; jt < jt0 + 2; jt++) {
    f32x4 acc = {0.f, 0.f, 0.f, 0.f};
#pragma unroll
    for (int ks = 0; ks < 4; ks++) {
      s16x8 bf = load8(w, (size_t)(jt * 16 + L) * EDIM + ks * 32 + quad * 8, fp32);
      acc = mfma32(a[ks], bf, acc);
    }
    float badd = loads(bias, jt * 16 + L, fp32);
#pragma unroll
    for (int r = 0; r < 4; r++) {
      size_t idx = (size_t)(mt + quad * 4 + r) * EDIM + jt * 16 + L;
      if (fp32) ((float*)outp)[idx] = acc[r] + badd;
      else      ((ushort*)outp)[idx] = f2bf(acc[r] + badd);
    }
  }
}

extern "C" void kernel_launch(void* const* d_in, const int* in_sizes, int n_in,
                              void* d_out, int out_size, void* d_ws, size_t ws_size,
                              hipStream_t stream) {
  const void* x   = d_in[0];
  const int*  adj = (const int*)d_in[1];
  const void* ipw = d_in[2];
  const void* ipb = d_in[3];
  const void* ow  = d_in[4];
  const void* ob  = d_in[5];

  char* ws = (char*)d_ws;
  ushort*   Qg  = (ushort*)(ws);
  ushort*   Kg  = (ushort*)(ws + ((size_t)4 << 20));
  _Float16* Vth = (_Float16*)(ws + ((size_t)8 << 20));
  uint32*   mb  = (uint32*)(ws + ((size_t)12 << 20));
  ushort*   Oa  = (ushort*)(ws + ((size_t)13 << 20));

  hipLaunchKernelGGL(k_pre, dim3(256, 22), dim3(256), 0, stream, x, ipw, ipb,
                     Qg, Kg, Vth, (const int4*)adj, mb);
  hipLaunchKernelGGL(k_attn, dim3(512), dim3(512), 0, stream, Qg, Kg, Vth, mb,
                     Oa);
  hipLaunchKernelGGL(k_proj, dim3(256, 4), dim3(256), 0, stream, d_out, Oa, ow, ob,
                     (const ushort*)x);
}